// Round 3
// baseline (563.697 us; speedup 1.0000x reference)
//
#include <hip/hip_runtime.h>
#include <math.h>

#define NB 36
#define HSTRIDE 37   // (37t+b)%32=(5t+b)%32 -> worst-case small-way aliasing, ~free

// Inline correctly-rounded-to-f32 atan2 via minimal f64 evaluation.
// No OCML call -> full cross-pixel ILP and no scratch spill.
// Reduction: atan(mn/mx) = 2*atan(q), q = mn/(mx+hyp) in [0, tan(pi/8)=0.414].
// Taylor deg 31 (alternating, exact coeffs): |trunc| <= 0.414^33/33 ~ 2^-47.
// Net relative error ~2^-45 -> ~30 of 67M pixels at 1-f32-ulp risk (harmless,
// see analysis); all reconstruction subtractions occur only at |angle|~pi/2,pi
// where absolute error stays << f32 ulp.
__device__ __forceinline__ float atan2f_cr(float gyf, float gxf) {
  double gx = (double)gxf, gy = (double)gyf;
  double ax = fabs(gx), ay = fabs(gy);
  double mn = fmin(ax, ay), mx = fmax(ax, ay);
  double h  = sqrt(fma(ax, ax, ay * ay));
  double den = mx + h;
  den = (den == 0.0) ? 1.0 : den;      // both-zero guard: q=0 -> a=0
  double q = mn / den;
  double t = q * q;
  double P = -1.0 / 31.0;
  P = fma(P, t,  1.0 / 29.0);
  P = fma(P, t, -1.0 / 27.0);
  P = fma(P, t,  1.0 / 25.0);
  P = fma(P, t, -1.0 / 23.0);
  P = fma(P, t,  1.0 / 21.0);
  P = fma(P, t, -1.0 / 19.0);
  P = fma(P, t,  1.0 / 17.0);
  P = fma(P, t, -1.0 / 15.0);
  P = fma(P, t,  1.0 / 13.0);
  P = fma(P, t, -1.0 / 11.0);
  P = fma(P, t,  1.0 / 9.0);
  P = fma(P, t, -1.0 / 7.0);
  P = fma(P, t,  1.0 / 5.0);
  P = fma(P, t, -1.0 / 3.0);
  P = fma(P, t,  1.0);
  double a = (2.0 * q) * P;                       // atan(mn/mx) in [0, pi/4]
  a = (ay > ax)   ? 1.5707963267948966 - a : a;   // swap octant
  a = (gx < 0.0)  ? 3.141592653589793  - a : a;   // left half-plane
  return (float)copysign(a, gy);                  // gy is never -0 here
}

// One THREAD per 32x32 patch; bit-exact sequential f32 pipeline (verified
// round 2, absmax 0.0): gradients/mag/binning f32 contract(off) in reference
// association order, CR-f32 atan2, per-bin accumulation in pixel order,
// sequential smooth + first-index argmax.
__global__ __launch_bounds__(256, 1) void orient_kernel(
    const float* __restrict__ x,
    const float* __restrict__ gk,
    float* __restrict__ out)
{
#pragma clang fp contract(off)
  __shared__ float gks[1024];
  __shared__ float hist[256 * HSTRIDE];

  const int t = threadIdx.x;
  const int p = blockIdx.x * 256 + t;

  for (int i = t; i < 1024; i += 256) gks[i] = gk[i];
  float* __restrict__ h = &hist[t * HSTRIDE];
  #pragma unroll
  for (int b = 0; b < NB; ++b) h[b] = 0.0f;
  __syncthreads();

  const float* __restrict__ xp = x + (size_t)p * 1024;

  const float PI_F  = 3.14159265358979323846f;   // 0x40490FDB
  const float TPI_F = 6.28318530717958647692f;   // 0x40C90FDB

  // rolling 3-row register window
  float prv[32], cur[32], nxt[32];
  {
    const float4* v0 = (const float4*)xp;
    #pragma unroll
    for (int q = 0; q < 8; ++q) {
      float4 a = v0[q];
      cur[4*q+0]=a.x; cur[4*q+1]=a.y; cur[4*q+2]=a.z; cur[4*q+3]=a.w;
    }
    #pragma unroll
    for (int j = 0; j < 32; ++j) prv[j] = cur[j];   // row -1 = replicate row 0
    const float4* v1 = (const float4*)(xp + 32);
    #pragma unroll
    for (int q = 0; q < 8; ++q) {
      float4 a = v1[q];
      nxt[4*q+0]=a.x; nxt[4*q+1]=a.y; nxt[4*q+2]=a.z; nxt[4*q+3]=a.w;
    }
  }

  for (int r = 0; r < 32; ++r) {
    #pragma unroll
    for (int j = 0; j < 32; ++j) {
      float left  = (j == 0)  ? cur[0]  : cur[j-1];   // replicate pad
      float right = (j == 31) ? cur[31] : cur[j+1];
      float gx = 0.5f * (left - right);
      float gy = 0.5f * (prv[j] - nxt[j]);
      float m2 = (gx*gx + gy*gy) + 1e-10f;            // ref association
      float mag = sqrtf(m2) * gks[r*32 + j];
      float ori = atan2f_cr(gy, gx);
      float ob  = (36.0f * (ori + PI_F)) / TPI_F;     // ref association
      float fo  = floorf(ob);
      float wo1 = ob - fo;
      int   b0  = (int)fo;
      if (b0 >= NB) b0 -= NB;                         // ob can hit exactly 36.0
      h[b0] += (1.0f - wo1) * mag;                    // sequential pixel order
    }
    if (r < 31) {
      #pragma unroll
      for (int j = 0; j < 32; ++j) { prv[j] = cur[j]; cur[j] = nxt[j]; }
      if (r < 30) {
        const float4* v2 = (const float4*)(xp + (size_t)(r + 2) * 32);
        #pragma unroll
        for (int q = 0; q < 8; ++q) {
          float4 a = v2[q];
          nxt[4*q+0]=a.x; nxt[4*q+1]=a.y; nxt[4*q+2]=a.z; nxt[4*q+3]=a.w;
        }
      }
    }
  }

  // zero-padded [0.33,0.34,0.33] smooth + first-index argmax (sequential).
  // /1024 skipped: exact pow2 scale, argmax-invariant.
  float best = -INFINITY; int bi = 0;
  #pragma unroll
  for (int i = 0; i < NB; ++i) {
    float ll = (i > 0)      ? h[i-1] : 0.0f;
    float rr = (i < NB - 1) ? h[i+1] : 0.0f;
    float sm = (0.33f*ll + 0.34f*h[i]) + 0.33f*rr;    // ref association
    if (sm > best) { best = sm; bi = i; }             // strict > == first-index
  }
  out[p] = -((TPI_F * (float)bi) / 36.0f - PI_F);
}

extern "C" void kernel_launch(void* const* d_in, const int* in_sizes, int n_in,
                              void* d_out, int out_size, void* d_ws, size_t ws_size,
                              hipStream_t stream) {
  const float* x  = (const float*)d_in[0];
  const float* gk = (const float*)d_in[1];
  float* out = (float*)d_out;
  const int B = in_sizes[0] / 1024;        // 65536 patches
  orient_kernel<<<B / 256, 256, 0, stream>>>(x, gk, out);
}

// Round 4
// 543.378 us; speedup vs baseline: 1.0374x; 1.0374x over previous
//
#include <hip/hip_runtime.h>
#include <math.h>

#define NB 36
#define HSTRIDE 37   // (37t+b)%32=(5t+b)%32 -> small-way lane aliasing, ~free

// Inline correctly-rounded-to-f32 atan2, f64 internal, NO sqrt and NO call.
// Octant reduce to t = mn/mx in [0,1]; if t > tan(pi/8): atan(t) = pi/4 +
// atan((mn-mx)/(mn+mx)). num/den are exact in f64 (sum/diff of two f32s),
// |q| <= tan(pi/8)=0.41421. Taylor deg 33 (exact coeffs, twice-validated
// family): first omitted term q^35/35 -> rel err ~2^-48; final f64->f32
// round == CR f32 atan2 except ~2^-48-proximity coincidences (negligible).
__device__ __forceinline__ float atan2f_cr(float gyf, float gxf) {
  double gx = (double)gxf, gy = (double)gyf;
  double ax = fabs(gx), ay = fabs(gy);
  double mn = fmin(ax, ay), mx = fmax(ax, ay);
  bool hi = mn > 0.41421356237309503 * mx;
  double num = hi ? (mn - mx) : mn;      // exact in f64
  double den = hi ? (mn + mx) : mx;      // exact in f64
  den = (den == 0.0) ? 1.0 : den;        // gx=gy=0 guard -> q=0 -> a=0
  double q = num / den;                  // CR f64 div, |q| <= 0.41422
  double t = q * q;
  double P =  1.0 / 33.0;
  P = fma(P, t, -1.0 / 31.0);
  P = fma(P, t,  1.0 / 29.0);
  P = fma(P, t, -1.0 / 27.0);
  P = fma(P, t,  1.0 / 25.0);
  P = fma(P, t, -1.0 / 23.0);
  P = fma(P, t,  1.0 / 21.0);
  P = fma(P, t, -1.0 / 19.0);
  P = fma(P, t,  1.0 / 17.0);
  P = fma(P, t, -1.0 / 15.0);
  P = fma(P, t,  1.0 / 13.0);
  P = fma(P, t, -1.0 / 11.0);
  P = fma(P, t,  1.0 / 9.0);
  P = fma(P, t, -1.0 / 7.0);
  P = fma(P, t,  1.0 / 5.0);
  P = fma(P, t, -1.0 / 3.0);
  P = fma(P, t,  1.0);
  double a = q * P;                                  // atan(q), sign of q
  a = hi        ? (0.7853981633974483  + a) : a;     // + pi/4
  a = (ay > ax) ? (1.5707963267948966  - a) : a;     // octant swap
  a = (gx < 0.0)? (3.141592653589793   - a) : a;     // left half-plane
  return (float)copysign(a, gy);
}

// Per-pixel bit-exact f32 pipeline (validated rounds 2-3, absmax 0.0):
// gradients/mag/binning f32 contract(off) in reference association order,
// CR-f32 atan2, per-bin accumulation in pixel order 0..1023.
#define PX(L, R, PV, NV, JJ) do {                                   \
    float gx_ = 0.5f * ((L) - (R));                                 \
    float gy_ = 0.5f * ((PV) - (NV));                               \
    float m2_ = ((gx_ * gx_) + (gy_ * gy_)) + 1e-10f;               \
    float mag_ = sqrtf(m2_) * gks[gb + (JJ)];                       \
    float ori_ = atan2f_cr(gy_, gx_);                               \
    float ob_ = (36.0f * (ori_ + PI_F)) / TPI_F;                    \
    float fo_ = floorf(ob_);                                        \
    float wo1_ = ob_ - fo_;                                         \
    int b0_ = (int)fo_;                                             \
    if (b0_ >= NB) b0_ -= NB;                                       \
    h[b0_] += (1.0f - wo1_) * mag_;                                 \
  } while (0)

#define QUAD(q, LV, RV) do {                                        \
    PX(LV,      c##q.y, p##q.x, n##q.x, 4*q+0);                     \
    PX(c##q.x,  c##q.z, p##q.y, n##q.y, 4*q+1);                     \
    PX(c##q.y,  c##q.w, p##q.z, n##q.z, 4*q+2);                     \
    PX(c##q.z,  RV,     p##q.w, n##q.w, 4*q+3);                     \
  } while (0)

// One THREAD per 32x32 patch. Rolling 3-row window as 24 NAMED float4s —
// no arrays, so no SROA failure, no scratch (round-3 counters showed the
// array version stuck at VGPR=72 = demoted to scratch).
__global__ __launch_bounds__(256, 1) void orient_kernel(
    const float* __restrict__ x,
    const float* __restrict__ gk,
    float* __restrict__ out)
{
#pragma clang fp contract(off)
  __shared__ float gks[1024];
  __shared__ float hist[256 * HSTRIDE];

  const int t = threadIdx.x;
  const int p = blockIdx.x * 256 + t;

  for (int i = t; i < 1024; i += 256) gks[i] = gk[i];
  float* __restrict__ h = &hist[t * HSTRIDE];
  #pragma unroll
  for (int b = 0; b < NB; ++b) h[b] = 0.0f;
  __syncthreads();

  const float4* __restrict__ xv = (const float4*)(x + (size_t)p * 1024);

  const float PI_F  = 3.14159265358979323846f;   // 0x40490FDB
  const float TPI_F = 6.28318530717958647692f;   // 0x40C90FDB

  float4 p0,p1,p2,p3,p4,p5,p6,p7;
  float4 c0,c1,c2,c3,c4,c5,c6,c7;
  float4 n0,n1,n2,n3,n4,n5,n6,n7;

  c0=xv[0]; c1=xv[1]; c2=xv[2]; c3=xv[3]; c4=xv[4]; c5=xv[5]; c6=xv[6]; c7=xv[7];
  p0=c0; p1=c1; p2=c2; p3=c3; p4=c4; p5=c5; p6=c6; p7=c7;     // row -1 = row 0
  n0=xv[8]; n1=xv[9]; n2=xv[10]; n3=xv[11]; n4=xv[12]; n5=xv[13]; n6=xv[14]; n7=xv[15];

  #pragma unroll 1
  for (int r = 0; r < 32; ++r) {
    const int gb = r << 5;
    QUAD(0, c0.x, c1.x);
    QUAD(1, c0.w, c2.x);
    QUAD(2, c1.w, c3.x);
    QUAD(3, c2.w, c4.x);
    QUAD(4, c3.w, c5.x);
    QUAD(5, c4.w, c6.x);
    QUAD(6, c5.w, c7.x);
    QUAD(7, c6.w, c7.w);
    if (r < 31) {
      p0=c0; p1=c1; p2=c2; p3=c3; p4=c4; p5=c5; p6=c6; p7=c7;
      c0=n0; c1=n1; c2=n2; c3=n3; c4=n4; c5=n5; c6=n6; c7=n7;
      if (r < 30) {
        const float4* nx = xv + (size_t)(r + 2) * 8;
        n0=nx[0]; n1=nx[1]; n2=nx[2]; n3=nx[3];
        n4=nx[4]; n5=nx[5]; n6=nx[6]; n7=nx[7];
      } else {
        n0=c0; n1=c1; n2=c2; n3=c3; n4=c4; n5=c5; n6=c6; n7=c7;  // row 32 = row 31
      }
    }
  }

  // zero-padded [0.33,0.34,0.33] smooth + first-index argmax (sequential).
  // /1024 skipped: exact pow2 scale, argmax-invariant.
  float best = -INFINITY; int bi = 0;
  #pragma unroll
  for (int i = 0; i < NB; ++i) {
    float ll = (i > 0)      ? h[i-1] : 0.0f;
    float rr = (i < NB - 1) ? h[i+1] : 0.0f;
    float sm = (0.33f*ll + 0.34f*h[i]) + 0.33f*rr;    // ref association
    if (sm > best) { best = sm; bi = i; }             // strict > == first-index
  }
  out[p] = -((TPI_F * (float)bi) / 36.0f - PI_F);
}

extern "C" void kernel_launch(void* const* d_in, const int* in_sizes, int n_in,
                              void* d_out, int out_size, void* d_ws, size_t ws_size,
                              hipStream_t stream) {
  const float* x  = (const float*)d_in[0];
  const float* gk = (const float*)d_in[1];
  float* out = (float*)d_out;
  const int B = in_sizes[0] / 1024;        // 65536 patches
  orient_kernel<<<B / 256, 256, 0, stream>>>(x, gk, out);
}

// Round 5
// 442.844 us; speedup vs baseline: 1.2729x; 1.2270x over previous
//
#include <hip/hip_runtime.h>
#include <math.h>

#define NB 36

// Inline correctly-rounded-to-f32 atan2, f64 internal, no call (validated
// rounds 2-4, absmax 0.0). Octant reduce to q in [-tan(pi/8), tan(pi/8)],
// Taylor deg 33 (exact coeffs): rel err ~2^-48 -> f64->f32 round == CR f32.
__device__ __forceinline__ float atan2f_cr(float gyf, float gxf) {
  double gx = (double)gxf, gy = (double)gyf;
  double ax = fabs(gx), ay = fabs(gy);
  double mn = fmin(ax, ay), mx = fmax(ax, ay);
  bool hi = mn > 0.41421356237309503 * mx;
  double num = hi ? (mn - mx) : mn;      // exact in f64
  double den = hi ? (mn + mx) : mx;      // exact in f64
  den = (den == 0.0) ? 1.0 : den;        // gx=gy=0 guard -> q=0 -> a=0
  double q = num / den;
  double t = q * q;
  double P =  1.0 / 33.0;
  P = fma(P, t, -1.0 / 31.0);
  P = fma(P, t,  1.0 / 29.0);
  P = fma(P, t, -1.0 / 27.0);
  P = fma(P, t,  1.0 / 25.0);
  P = fma(P, t, -1.0 / 23.0);
  P = fma(P, t,  1.0 / 21.0);
  P = fma(P, t, -1.0 / 19.0);
  P = fma(P, t,  1.0 / 17.0);
  P = fma(P, t, -1.0 / 15.0);
  P = fma(P, t,  1.0 / 13.0);
  P = fma(P, t, -1.0 / 11.0);
  P = fma(P, t,  1.0 / 9.0);
  P = fma(P, t, -1.0 / 7.0);
  P = fma(P, t,  1.0 / 5.0);
  P = fma(P, t, -1.0 / 3.0);
  P = fma(P, t,  1.0);
  double a = q * P;
  a = hi        ? (0.7853981633974483 + a) : a;
  a = (ay > ax) ? (1.5707963267948966 - a) : a;
  a = (gx < 0.0)? (3.141592653589793  - a) : a;
  return (float)copysign(a, gy);
}

// Exact f32 per-pixel pipeline (validated rounds 2-4): contract(off),
// reference association order, CR atan2, per-lane hist += in pixel order.
#define PX(L, R, UP, DN, G) do {                                    \
    float gx_ = 0.5f * ((L) - (R));                                 \
    float gy_ = 0.5f * ((UP) - (DN));                               \
    float m2_ = ((gx_ * gx_) + (gy_ * gy_)) + 1e-10f;               \
    float mag_ = sqrtf(m2_) * (G);                                  \
    float ori_ = atan2f_cr(gy_, gx_);                               \
    float ob_ = (36.0f * (ori_ + PI_F)) / TPI_F;                    \
    float fo_ = floorf(ob_);                                        \
    float wo1_ = ob_ - fo_;                                         \
    int b0_ = (int)fo_;                                             \
    if (b0_ >= NB) b0_ -= NB;                                       \
    h[b0_] += (1.0f - wo1_) * mag_;                                 \
  } while (0)

#define QUAD(cq, uq, dq, gq, LV, RV) do {                           \
    PX(LV,   cq.y, uq.x, dq.x, gq.x);                               \
    PX(cq.x, cq.z, uq.y, dq.y, gq.y);                               \
    PX(cq.y, cq.w, uq.z, dq.z, gq.z);                               \
    PX(cq.z, RV,   uq.w, dq.w, gq.w);                               \
  } while (0)

#define UP1(v) __shfl_up((v), 1, 32)
#define DN1(v) __shfl_down((v), 1, 32)

// One WAVE per 32x32 patch. lane = row + 32*half; lane owns 16 contiguous
// pixels (row, cols half*16..+15) -> all loads hit the wave's own 4KB patch;
// vertical stencil = shfl +-1 width 32 (clamp == replicate pad), half
// boundary = one shfl_xor(32). Per-LANE 36-bin LDS hist (stride 37: bank
// (5*lane+b)%32 -> <=2-way, free), accumulated in each lane's ascending
// pixel order; then per-bin reduction over the 64 lane-hists in pixel-RUN
// order (the only deviation from the reference's fully-sequential sum:
// run-partial regrouping, ~ulp noise, argmax-safe w.h.p.). No block syncs:
// all LDS traffic is intra-wave (DS ops in-order per wave).
__global__ __launch_bounds__(256, 4) void orient_kernel(
    const float* __restrict__ x,
    const float* __restrict__ gk,
    float* __restrict__ out)
{
#pragma clang fp contract(off)
  __shared__ float hist[256 * 37];   // 37888 B -> 4 blocks/CU

  const int t    = threadIdx.x;
  const int lane = t & 63;
  const int row  = lane & 31;
  const int half = lane >> 5;
  const int p    = (blockIdx.x * 256 + t) >> 6;   // global wave id == patch

  const float PI_F  = 3.14159265358979323846f;   // 0x40490FDB
  const float TPI_F = 6.28318530717958647692f;   // 0x40C90FDB

  float* __restrict__ h = &hist[t * 37];
  #pragma unroll
  for (int b = 0; b < NB; ++b) h[b] = 0.0f;

  const float4* __restrict__ xv =
      (const float4*)(x + (size_t)p * 1024 + (row * 32 + half * 16));
  const float4* __restrict__ gv = (const float4*)(gk + (row * 32 + half * 16));
  float4 c0 = xv[0], c1 = xv[1], c2 = xv[2], c3 = xv[3];
  float4 g0 = gv[0], g1 = gv[1], g2 = gv[2], g3 = gv[3];

  float4 u0, u1, u2, u3, d0, d1, d2, d3;
  u0.x=UP1(c0.x); u0.y=UP1(c0.y); u0.z=UP1(c0.z); u0.w=UP1(c0.w);
  u1.x=UP1(c1.x); u1.y=UP1(c1.y); u1.z=UP1(c1.z); u1.w=UP1(c1.w);
  u2.x=UP1(c2.x); u2.y=UP1(c2.y); u2.z=UP1(c2.z); u2.w=UP1(c2.w);
  u3.x=UP1(c3.x); u3.y=UP1(c3.y); u3.z=UP1(c3.z); u3.w=UP1(c3.w);
  d0.x=DN1(c0.x); d0.y=DN1(c0.y); d0.z=DN1(c0.z); d0.w=DN1(c0.w);
  d1.x=DN1(c1.x); d1.y=DN1(c1.y); d1.z=DN1(c1.z); d1.w=DN1(c1.w);
  d2.x=DN1(c2.x); d2.y=DN1(c2.y); d2.z=DN1(c2.z); d2.w=DN1(c2.w);
  d3.x=DN1(c3.x); d3.y=DN1(c3.y); d3.z=DN1(c3.z); d3.w=DN1(c3.w);

  float send = half ? c0.x : c3.w;
  float recv = __shfl_xor(send, 32, 64);
  float LB = half ? recv : c0.x;    // left neighbor of this chunk's col 0
  float RB = half ? c3.w : recv;    // right neighbor of this chunk's col 15

  QUAD(c0, u0, d0, g0, LB,   c1.x);
  QUAD(c1, u1, d1, g1, c0.w, c2.x);
  QUAD(c2, u2, d2, g2, c1.w, c3.x);
  QUAD(c3, u3, d3, g3, c2.w, RB);

  __builtin_amdgcn_wave_barrier();   // keep phase order; DS in-order per wave

  // per-bin reduction over lane-hists in pixel-run order:
  // run k covers pixels [k*16, k*16+16) -> owning lane = (k>>1) + 32*(k&1)
  const float* __restrict__ hw = &hist[(t >> 6) * 2368];
  const int bb = (lane < NB) ? lane : NB - 1;     // clamp; masked later
  float s = 0.0f;
  #pragma unroll
  for (int k = 0; k < 64; ++k) {
    const int l = (k >> 1) + ((k & 1) << 5);
    s += hw[l * 37 + bb];
  }

  // zero-padded [0.33,0.34,0.33] smooth + 64-lane first-index argmax
  float ll = __shfl(s, lane - 1);
  float rr = __shfl(s, lane + 1);
  float v; int idx;
  if (lane < NB) {
    float sl = (lane > 0)      ? ll : 0.0f;
    float sr = (lane < NB - 1) ? rr : 0.0f;
    v = (0.33f * sl + 0.34f * s) + 0.33f * sr;    // ref association
    idx = lane;
  } else {
    v = -INFINITY; idx = 1 << 20;
  }
  #pragma unroll
  for (int off = 32; off > 0; off >>= 1) {
    float v2 = __shfl_xor(v, off, 64);
    int   i2 = __shfl_xor(idx, off, 64);
    if (v2 > v || (v2 == v && i2 < idx)) { v = v2; idx = i2; }
  }
  if (lane == 0) {
    out[p] = -((TPI_F * (float)idx) / 36.0f - PI_F);
  }
}

extern "C" void kernel_launch(void* const* d_in, const int* in_sizes, int n_in,
                              void* d_out, int out_size, void* d_ws, size_t ws_size,
                              hipStream_t stream) {
  const float* x  = (const float*)d_in[0];
  const float* gk = (const float*)d_in[1];
  float* out = (float*)d_out;
  const int B = in_sizes[0] / 1024;        // 65536 patches
  orient_kernel<<<B / 4, 256, 0, stream>>>(x, gk, out);
}